// Round 7
// baseline (459.693 us; speedup 1.0000x reference)
//
#include <hip/hip_runtime.h>
#include <hip/hip_bf16.h>
#include <stdint.h>

#define BATCH 128
#define SEQ   512
#define NW    6
#define DIM   64
#define NELEM (BATCH * SEQ * NW)   // 393216
#define PI_F  3.14159265358979323846f

typedef float v2f __attribute__((ext_vector_type(2)));
typedef uint16_t u16x8 __attribute__((ext_vector_type(8)));

__device__ __forceinline__ v2f pkfma(float s, v2f m, v2f a) {
    return __builtin_elementwise_fma((v2f){s, s}, m, a);
}

// DPP move: v[lane] = v[src(lane)] per CTRL (all source lanes valid).
template <int CTRL>
__device__ __forceinline__ float dpp_mov(float x) {
    return __int_as_float(__builtin_amdgcn_update_dpp(
        0, __float_as_int(x), CTRL, 0xF, 0xF, false));
}

// DPP add stage with bound_ctrl=true (folds to v_add_f32_dpp).
template <int CTRL>
__device__ __forceinline__ float dpp_add(float v) {
    return v + __int_as_float(__builtin_amdgcn_update_dpp(
        0, __float_as_int(v), CTRL, 0xF, 0xF, true));
}

// permlane swap-add: with a=b=v, r[0]+r[1] = pair-sum broadcast (r6-verified).
__device__ __forceinline__ float swap16_add(float v) {
    auto r = __builtin_amdgcn_permlane16_swap(
        __float_as_int(v), __float_as_int(v), false, false);
    return __int_as_float((int)r[0]) + __int_as_float((int)r[1]);
}
__device__ __forceinline__ float swap32_add(float v) {
    auto r = __builtin_amdgcn_permlane32_swap(
        __float_as_int(v), __float_as_int(v), false, false);
    return __int_as_float((int)r[0]) + __int_as_float((int)r[1]);
}

__device__ __forceinline__ float ldf(const void* p, int i, bool bf) {
    if (bf) {
        uint32_t u = (uint32_t)((const uint16_t*)p)[i];
        return __uint_as_float(u << 16);
    }
    return ((const float*)p)[i];
}

// ---------------------------------------------------------------------------
// Kernel 1 (msetup + misc):
//  - blocks [0,32): 4 waves/block evolve one (dir,col) basis column; writes
//    the pair-major transposed Mgt (ALL 32 col-pairs; r3-verified pattern)
//  - block 32: misc fills + flag post
// ---------------------------------------------------------------------------
__global__ void k_prep(const void* ang, const void* poly, const void* fp,
                       const void* bp, const void* fc, const void* bc,
                       float* __restrict__ misc, float* __restrict__ Mgt,
                       int* __restrict__ flag) {
    __shared__ int cnt;
    if (threadIdx.x == 0) cnt = 0;
    __syncthreads();
    {
        uint32_t w = ((const uint32_t*)ang)[threadIdx.x & 255];
        uint32_t e = (w >> 8) & 0xFFu;
        if (e >= 0x3Au && e <= 0x41u) atomicAdd(&cnt, 1);
    }
    __syncthreads();
    const bool bf = (cnt >= 128);

    if (blockIdx.x == 32) {
        if (threadIdx.x == 0)      misc[76] = ldf(fc, 0, bf);
        else if (threadIdx.x == 1) misc[77] = ldf(bc, 0, bf);
        else if (threadIdx.x == 2) *flag = bf ? 1 : 0;
        return;
    }

    // ---- msetup path: 4 columns per block (one per wave) ----
    const int lane = threadIdx.x & 63;
    const int tix  = blockIdx.x * 4 + (threadIdx.x >> 6);
    const int dir  = tix >> 6;
    const int col  = tix & 63;
    const void* prm = dir ? bp : fp;
    const int p = lane;

    float yr = (p == col) ? 1.f : 0.f;
    float yi = 0.f;

#pragma unroll
    for (int d = 0; d < 4; ++d) {
        const float th = 0.5f * PI_F * ldf(poly, d, bf) *
                         (float)(6 - 2 * (int)__popc((unsigned)p));
        float s, c;
        __sincosf(th, &s, &c);
        const float nr = yr * c + yi * s;
        const float ni = yi * c - yr * s;
        yr = nr; yi = ni;
#pragma unroll
        for (int k = 0; k < 6; ++k) {
            const int cw = k, tw = (k + 1) % 6;
            const int src = p ^ (((p >> (5 - cw)) & 1) << (5 - tw));
            yr = __shfl(yr, src, 64);
            yi = __shfl(yi, src, 64);
        }
    }

    int idx = 0;
#pragma unroll
    for (int l = 0; l < 2; ++l) {
#pragma unroll
        for (int w = 0; w < 6; ++w) {
            float cx, sx, cy, sy, cz, sz;
            __sincosf(0.5f * ldf(prm, idx + 0, bf), &sx, &cx);
            __sincosf(0.5f * ldf(prm, idx + 1, bf), &sy, &cy);
            __sincosf(0.5f * ldf(prm, idx + 2, bf), &sz, &cz);
            idx += 3;
            const float A = cy * cx, B = sy * sx, C = sy * cx, D = cy * sx;
            const float U00r = cz * A + sz * B, U00i = cz * B - sz * A;
            const float U11r = U00r,            U11i = sz * A - cz * B;
            const float Xr   = cz * C + sz * D, Xi   = sz * C - cz * D;
            const int m  = 1 << (5 - w);
            const int bb = (p >> (5 - w)) & 1;
            const float C1r = bb ? U11r : U00r;
            const float C1i = bb ? U11i : U00i;
            const float C2r = bb ? Xr : -Xr;
            const float C2i = Xi;
            const float pr = __shfl_xor(yr, m, 64);
            const float pi = __shfl_xor(yi, m, 64);
            const float nr = C1r * yr - C1i * yi + C2r * pr - C2i * pi;
            const float ni = C1r * yi + C1i * yr + C2r * pi + C2i * pr;
            yr = nr; yi = ni;
        }
#pragma unroll
        for (int k = 0; k < 5; ++k) {
            const int src = p ^ (((p >> (5 - k)) & 1) << (5 - (k + 1)));
            yr = __shfl(yr, src, 64);
            yi = __shfl(yi, src, 64);
        }
    }

    // pair-major transpose, all 32 pairs (k_sim streams this from LDS)
    float2* mt = (float2*)(Mgt +
        (((size_t)(dir * 32 + (col >> 1)) * 64 + p) * 2 + (col & 1)) * 2);
    *mt = (float2){yr, yi};
}

// ---------------------------------------------------------------------------
// Kernel 2: recurrent sim — ONE wave per chain; M streamed from LDS.
//   * M (32 KB/dir) staged once into mlds[pair][lane] (conflict-free 1KB
//     pattern). Per step: 32 ds_read_b128 on the otherwise-idle DS pipe,
//     2-window A/B rotation (32 regs) -> register pressure ~100, no spill
//     possible (the r1/r3/r4 failure mode).
//   * zero barriers, zero exchange: full matvec per lane via the eH x eL
//     contraction; measurement all-VALU (r6-verified dots + reduce-to-all).
//   * packed (v2f) sincos; xq read between matvec and dots (late, covered).
//   * asm-opaque mlp pointer stops LICM from hoisting the loop-invariant
//     ds_reads into 128 live regs.
//   * z stored directly to global by lane 0 (zb deleted -> cl+mlds fit 64KB).
// ---------------------------------------------------------------------------
__global__ void __launch_bounds__(64, 1) k_sim(const void* __restrict__ ang,
                                               const float* __restrict__ Mgt,
                                               float* __restrict__ hbuf,
                                               const int* __restrict__ flag) {
    const int lane  = threadIdx.x;           // 0..63, one wave
    const int chain = blockIdx.x;            // 0..255
    const int dir   = chain >> 7;
    const int b     = chain & 127;
    const bool bf   = (*flag != 0);

    __shared__ __align__(16) float  cl[SEQ * 12];   // 24 KB cos/sin(x)
    __shared__ __align__(16) float4 mlds[32 * 64];  // 32 KB M (pair-major)

    // ---- stage: convert this chain's 3072 angles -> cos/sin in LDS ----
    if (!bf) {
        const float4* src =
            (const float4*)((const float*)ang + (size_t)b * (SEQ * NW));
#pragma unroll
        for (int k = 0; k < 12; ++k) {
            const int v = k * 64 + lane;          // float4 index 0..767
            const float4 a = src[v];
            __align__(16) float o[8];
            float s, c;
            __sincosf(a.x, &s, &c); o[0] = c; o[1] = s;
            __sincosf(a.y, &s, &c); o[2] = c; o[3] = s;
            __sincosf(a.z, &s, &c); o[4] = c; o[5] = s;
            __sincosf(a.w, &s, &c); o[6] = c; o[7] = s;
            ((float4*)cl)[2 * v]     = ((const float4*)o)[0];
            ((float4*)cl)[2 * v + 1] = ((const float4*)o)[1];
        }
    } else {
        const u16x8* src =
            (const u16x8*)((const uint16_t*)ang + (size_t)b * (SEQ * NW));
#pragma unroll
        for (int k = 0; k < 6; ++k) {
            const int v = k * 64 + lane;          // u16x8 index 0..383
            const u16x8 a = src[v];
            __align__(16) float o[16];
#pragma unroll
            for (int e = 0; e < 8; ++e) {
                const float x = __uint_as_float(((uint32_t)a[e]) << 16);
                float s, c;
                __sincosf(x, &s, &c);
                o[2 * e] = c; o[2 * e + 1] = s;
            }
#pragma unroll
            for (int j = 0; j < 4; ++j)
                ((float4*)cl)[4 * v + j] = ((const float4*)o)[j];
        }
    }

    // ---- stage: this dir's M into LDS (pair-major, conflict-free) ----
    {
        const float4* mgt4 = (const float4*)Mgt;
#pragma unroll
        for (int k = 0; k < 32; ++k)
            mlds[k * 64 + lane] = mgt4[(size_t)(dir * 32 + k) * 64 + lane];
    }

    // per-wire Z sign masks
    int zmask[6];
#pragma unroll
    for (int w = 0; w < 6; ++w) zmask[w] = ((lane >> (5 - w)) & 1) << 31;

    // walking pointers
    const float* cp = cl + (dir ? (SEQ - 1) * 12 : 0);
    const int   cstep = dir ? -12 : 12;
    float* zo = hbuf + (size_t)dir * NELEM + (size_t)b * (SEQ * NW) +
                (dir ? (SEQ - 1) * NW : 0);
    const int   zstep = dir ? -NW : NW;

    float h[6] = {0.f, 0.f, 0.f, 0.f, 0.f, 0.f};

    __syncthreads();   // staging LDS writes visible

    // opaque per-iteration pointer (blocks LICM of the M ds_reads)
    const float4* mlp = ((const float4*)mlds) + lane;

#define LOADW(W, G) { W[0] = mlp[((G)*4+0)*64]; W[1] = mlp[((G)*4+1)*64]; \
                      W[2] = mlp[((G)*4+2)*64]; W[3] = mlp[((G)*4+3)*64]; }
#define CONSUME(W, G) { v2f n = {0.f, 0.f}; \
        n = pkfma(eL[0], (v2f){W[0].x, W[0].y}, n); \
        n = pkfma(eL[1], (v2f){W[0].z, W[0].w}, n); \
        n = pkfma(eL[2], (v2f){W[1].x, W[1].y}, n); \
        n = pkfma(eL[3], (v2f){W[1].z, W[1].w}, n); \
        n = pkfma(eL[4], (v2f){W[2].x, W[2].y}, n); \
        n = pkfma(eL[5], (v2f){W[2].z, W[2].w}, n); \
        n = pkfma(eL[6], (v2f){W[3].x, W[3].y}, n); \
        n = pkfma(eL[7], (v2f){W[3].z, W[3].w}, n); \
        y = pkfma(eH[G], n, y); }

    float4 A[4], B[4];
    LOADW(A, 0)
    LOADW(B, 1)

    for (int t = 0; t < SEQ; ++t) {
        asm volatile("" : "+v"(mlp));   // keep M reads inside the loop

        // packed sincos(h/2): 3 v2f pairs (same polynomial as r6, bitwise)
        v2f hp0 = {h[0], h[1]}, hp1 = {h[2], h[3]}, hp2 = {h[4], h[5]};
        float cw[6], sw[6];
        {
            const v2f kc1 = {2.6041667e-3f, 2.6041667e-3f};
            const v2f kc0 = {-0.125f, -0.125f};
            const v2f ks1 = {2.6041667e-4f, 2.6041667e-4f};
            const v2f ks0 = {-2.0833333e-2f, -2.0833333e-2f};
            const v2f one = {1.f, 1.f}, half = {0.5f, 0.5f};
            v2f u0 = hp0 * hp0, u1 = hp1 * hp1, u2 = hp2 * hp2;
            v2f c0 = __builtin_elementwise_fma(u0,
                        __builtin_elementwise_fma(u0, kc1, kc0), one);
            v2f c1 = __builtin_elementwise_fma(u1,
                        __builtin_elementwise_fma(u1, kc1, kc0), one);
            v2f c2 = __builtin_elementwise_fma(u2,
                        __builtin_elementwise_fma(u2, kc1, kc0), one);
            v2f s0 = hp0 * __builtin_elementwise_fma(u0,
                        __builtin_elementwise_fma(u0, ks1, ks0), half);
            v2f s1 = hp1 * __builtin_elementwise_fma(u1,
                        __builtin_elementwise_fma(u1, ks1, ks0), half);
            v2f s2 = hp2 * __builtin_elementwise_fma(u2,
                        __builtin_elementwise_fma(u2, ks1, ks0), half);
            cw[0] = c0.x; cw[1] = c0.y; cw[2] = c1.x; cw[3] = c1.y;
            cw[4] = c2.x; cw[5] = c2.y;
            sw[0] = s0.x; sw[1] = s0.y; sw[2] = s1.x; sw[3] = s1.y;
            sw[4] = s2.x; sw[5] = s2.y;
        }

        // e(h) = eH (wires 0-2) ⊗ eL (wires 3-5)  (r1-verified)
        float g01[4], g45[4], eH[8], eL[8];
        g01[0] = cw[0] * cw[1]; g01[1] = cw[0] * sw[1];
        g01[2] = sw[0] * cw[1]; g01[3] = sw[0] * sw[1];
        g45[0] = cw[4] * cw[5]; g45[1] = cw[4] * sw[5];
        g45[2] = sw[4] * cw[5]; g45[3] = sw[4] * sw[5];
#pragma unroll
        for (int j = 0; j < 8; ++j) {
            eH[j] = g01[j >> 1] * ((j & 1) ? sw[2] : cw[2]);
            eL[j] = ((j >> 2) ? sw[3] : cw[3]) * g45[j & 3];
        }

        // y[lane] = sum_c M[lane,c] e[c]: 8 chunks, A/B window rotation
        v2f y = {0.f, 0.f};
        CONSUME(A, 0) LOADW(A, 2)
        CONSUME(B, 1) LOADW(B, 3)
        CONSUME(A, 2) LOADW(A, 4)
        CONSUME(B, 3) LOADW(B, 5)
        CONSUME(A, 4) LOADW(A, 6)
        CONSUME(B, 5) LOADW(B, 7)
        CONSUME(A, 6)
        CONSUME(B, 7)

        // this step's cos/sin(x) — needed only below at v-build
        const float4 xq0 = ((const float4*)cp)[0];
        const float4 xq1 = ((const float4*)cp)[1];
        const float4 xq2 = ((const float4*)cp)[2];
        cp += cstep;

        const float yr = y.x, yi = y.y;
        const int yri = __float_as_int(yr), yii = __float_as_int(yi);

        // dots y[l]·y[l^m] (r6-verified, all VALU)
        float dot[6];
        {
            auto rr = __builtin_amdgcn_permlane32_swap(yri, yri, false, false);
            auto ri = __builtin_amdgcn_permlane32_swap(yii, yii, false, false);
            dot[0] = fmaf(__int_as_float((int)rr[0]), __int_as_float((int)rr[1]),
                          __int_as_float((int)ri[0]) * __int_as_float((int)ri[1]));
        }
        {
            auto rr = __builtin_amdgcn_permlane16_swap(yri, yri, false, false);
            auto ri = __builtin_amdgcn_permlane16_swap(yii, yii, false, false);
            dot[1] = fmaf(__int_as_float((int)rr[0]), __int_as_float((int)rr[1]),
                          __int_as_float((int)ri[0]) * __int_as_float((int)ri[1]));
        }
        dot[2] = fmaf(yr, dpp_mov<0x128>(yr), yi * dpp_mov<0x128>(yi)); // xor8
        dot[3] = fmaf(yr, dpp_mov<0x141>(dpp_mov<0x1B>(yr)),            // xor4
                      yi * dpp_mov<0x141>(dpp_mov<0x1B>(yi)));
        dot[4] = fmaf(yr, dpp_mov<0x4E>(yr), yi * dpp_mov<0x4E>(yi));   // xor2
        dot[5] = fmaf(yr, dpp_mov<0xB1>(yr), yi * dpp_mov<0xB1>(yi));   // xor1

        const float q = fmaf(yr, yr, yi * yi);
        const float cx[6] = {xq0.x, xq0.z, xq1.x, xq1.z, xq2.x, xq2.z};
        const float sx[6] = {xq0.y, xq0.w, xq1.y, xq1.w, xq2.y, xq2.w};

        float v[6];
#pragma unroll
        for (int w = 0; w < 6; ++w) {
            const float cq = __int_as_float(__float_as_int(cx[w] * q) ^ zmask[w]);
            v[w] = fmaf(-sx[w], dot[w], cq);
        }

        // butterfly reduce-to-ALL (r6-verified)
#pragma unroll
        for (int k = 0; k < 6; ++k) v[k] = dpp_add<0xB1>(v[k]);   // xor1
#pragma unroll
        for (int k = 0; k < 6; ++k) v[k] = dpp_add<0x4E>(v[k]);   // xor2
#pragma unroll
        for (int k = 0; k < 6; ++k) v[k] = dpp_add<0x141>(v[k]);  // ^7 ≡ xor4
#pragma unroll
        for (int k = 0; k < 6; ++k) v[k] = dpp_add<0x140>(v[k]);  // ^15 ≡ xor8
#pragma unroll
        for (int k = 0; k < 6; ++k) v[k] = swap16_add(v[k]);
#pragma unroll
        for (int k = 0; k < 6; ++k) v[k] = swap32_add(v[k]);

        // prefetch next iteration's chunks 0,1 during the store/update tail
        LOADW(A, 0)
        LOADW(B, 1)

        if (lane == 0) {                       // totals on all lanes
            *(float2*)(zo)     = (float2){v[0], v[1]};
            *(float2*)(zo + 2) = (float2){v[2], v[3]};
            *(float2*)(zo + 4) = (float2){v[4], v[5]};
        }
        zo += zstep;
#pragma unroll
        for (int w = 0; w < 6; ++w) h[w] = v[w];
    }
#undef LOADW
#undef CONSUME
}

// ---------------------------------------------------------------------------
// Kernel 3: out = sigmoid(fc)*h_fwd + sigmoid(bc)*h_bwd, dtype per flag.
// ---------------------------------------------------------------------------
__global__ void k_combine(const float* __restrict__ hbuf,
                          const float* __restrict__ misc,
                          void* __restrict__ out, const int* __restrict__ flag) {
    const int i = blockIdx.x * blockDim.x + threadIdx.x;
    if (i >= NELEM) return;
    const float sf = 1.f / (1.f + __expf(-misc[76]));
    const float sb = 1.f / (1.f + __expf(-misc[77]));
    const float v = sf * hbuf[i] + sb * hbuf[NELEM + i];
    if (*flag) ((__hip_bfloat16*)out)[i] = __float2bfloat16(v);
    else       ((float*)out)[i] = v;
}

// ---------------------------------------------------------------------------
extern "C" void kernel_launch(void* const* d_in, const int* in_sizes, int n_in,
                              void* d_out, int out_size, void* d_ws, size_t ws_size,
                              hipStream_t stream) {
    const void* ang  = d_in[0];
    const void* poly = d_in[1];
    const void* fp   = d_in[2];
    const void* bp   = d_in[3];
    const void* fc   = d_in[4];
    const void* bc   = d_in[5];

    // ws (floats): pad[32] | misc[128] | hbuf[2*NELEM] | Mgt[16384] | flag
    float* misc = (float*)d_ws + 32;
    float* hbuf = misc + 128;
    float* Mgt  = hbuf + 2 * NELEM;
    int*   flag = (int*)(Mgt + 2 * 32 * 64 * 4);

    k_prep<<<33, 256, 0, stream>>>(ang, poly, fp, bp, fc, bc, misc, Mgt, flag);
    k_sim<<<256, 64, 0, stream>>>(ang, Mgt, hbuf, flag);
    k_combine<<<(NELEM + 255) / 256, 256, 0, stream>>>(hbuf, misc, d_out, flag);
}

// Round 8
// 344.130 us; speedup vs baseline: 1.3358x; 1.3358x over previous
//
#include <hip/hip_runtime.h>
#include <hip/hip_bf16.h>
#include <stdint.h>

#define BATCH 128
#define SEQ   512
#define NW    6
#define DIM   64
#define NELEM (BATCH * SEQ * NW)   // 393216
#define PI_F  3.14159265358979323846f

typedef float v2f __attribute__((ext_vector_type(2)));
typedef uint16_t u16x8 __attribute__((ext_vector_type(8)));

__device__ __forceinline__ v2f pkfma(float s, v2f m, v2f a) {
    return __builtin_elementwise_fma((v2f){s, s}, m, a);
}

// Single-instruction DPP add stage: bound_ctrl=true -> invalid lanes read 0,
// identical to the old (old=0, false) form, but folds to v_add_f32_dpp.
template <int CTRL>
__device__ __forceinline__ float dpp_add(float v) {
    return v + __int_as_float(__builtin_amdgcn_update_dpp(
        0, __float_as_int(v), CTRL, 0xF, 0xF, true));
}

// 6-way interleaved reduction stage (r0/r1-verified sequence shr1,2,4,8 +
// bcast15,31 -> totals land in lane 63).
template <int CTRL>
__device__ __forceinline__ void red6(float v[6]) {
#pragma unroll
    for (int k = 0; k < 6; ++k) v[k] = dpp_add<CTRL>(v[k]);
}

// DPP move, bound_ctrl=true (all CTRLs used are valid on every lane ->
// folds to a single v_mov_b32_dpp).
template <int CTRL>
__device__ __forceinline__ float dpp_mov(float x) {
    return __int_as_float(__builtin_amdgcn_update_dpp(
        0, __float_as_int(x), CTRL, 0xF, 0xF, true));
}

__device__ __forceinline__ float ldf(const void* p, int i, bool bf) {
    if (bf) {
        uint32_t u = (uint32_t)((const uint16_t*)p)[i];
        return __uint_as_float(u << 16);
    }
    return ((const float*)p)[i];
}

// ---------------------------------------------------------------------------
// Kernel 1 (msetup + misc):
//  - blocks [0,32): 4 waves/block evolve one (dir,col) basis column -> Mg
//  - block 32: misc fills + flag post
// ---------------------------------------------------------------------------
__global__ void k_prep(const void* ang, const void* poly, const void* fp,
                       const void* bp, const void* fc, const void* bc,
                       float* __restrict__ misc, float* __restrict__ Mg,
                       int* __restrict__ flag) {
    __shared__ int cnt;
    if (threadIdx.x == 0) cnt = 0;
    __syncthreads();
    {
        uint32_t w = ((const uint32_t*)ang)[threadIdx.x & 255];
        uint32_t e = (w >> 8) & 0xFFu;
        if (e >= 0x3Au && e <= 0x41u) atomicAdd(&cnt, 1);
    }
    __syncthreads();
    const bool bf = (cnt >= 128);

    if (blockIdx.x == 32) {
        if (threadIdx.x == 0)      misc[76] = ldf(fc, 0, bf);
        else if (threadIdx.x == 1) misc[77] = ldf(bc, 0, bf);
        else if (threadIdx.x == 2) *flag = bf ? 1 : 0;
        return;
    }

    // ---- msetup path: 4 columns per block (one per wave) ----
    const int lane = threadIdx.x & 63;
    const int tix  = blockIdx.x * 4 + (threadIdx.x >> 6);
    const int dir  = tix >> 6;
    const int col  = tix & 63;
    const void* prm = dir ? bp : fp;
    const int p = lane;

    float yr = (p == col) ? 1.f : 0.f;
    float yi = 0.f;

#pragma unroll
    for (int d = 0; d < 4; ++d) {
        const float th = 0.5f * PI_F * ldf(poly, d, bf) *
                         (float)(6 - 2 * (int)__popc((unsigned)p));
        float s, c;
        __sincosf(th, &s, &c);
        const float nr = yr * c + yi * s;
        const float ni = yi * c - yr * s;
        yr = nr; yi = ni;
#pragma unroll
        for (int k = 0; k < 6; ++k) {
            const int cw = k, tw = (k + 1) % 6;
            const int src = p ^ (((p >> (5 - cw)) & 1) << (5 - tw));
            yr = __shfl(yr, src, 64);
            yi = __shfl(yi, src, 64);
        }
    }

    int idx = 0;
#pragma unroll
    for (int l = 0; l < 2; ++l) {
#pragma unroll
        for (int w = 0; w < 6; ++w) {
            float cx, sx, cy, sy, cz, sz;
            __sincosf(0.5f * ldf(prm, idx + 0, bf), &sx, &cx);
            __sincosf(0.5f * ldf(prm, idx + 1, bf), &sy, &cy);
            __sincosf(0.5f * ldf(prm, idx + 2, bf), &sz, &cz);
            idx += 3;
            const float A = cy * cx, B = sy * sx, C = sy * cx, D = cy * sx;
            const float U00r = cz * A + sz * B, U00i = cz * B - sz * A;
            const float U11r = U00r,            U11i = sz * A - cz * B;
            const float Xr   = cz * C + sz * D, Xi   = sz * C - cz * D;
            const int m  = 1 << (5 - w);
            const int bb = (p >> (5 - w)) & 1;
            const float C1r = bb ? U11r : U00r;
            const float C1i = bb ? U11i : U00i;
            const float C2r = bb ? Xr : -Xr;
            const float C2i = Xi;
            const float pr = __shfl_xor(yr, m, 64);
            const float pi = __shfl_xor(yi, m, 64);
            const float nr = C1r * yr - C1i * yi + C2r * pr - C2i * pi;
            const float ni = C1r * yi + C1i * yr + C2r * pi + C2i * pr;
            yr = nr; yi = ni;
        }
#pragma unroll
        for (int k = 0; k < 5; ++k) {
            const int src = p ^ (((p >> (5 - k)) & 1) << (5 - (k + 1)));
            yr = __shfl(yr, src, 64);
            yi = __shfl(yi, src, 64);
        }
    }

    float* out = Mg + ((size_t)(dir * 64 + p) * 64 + (size_t)col) * 2;
    out[0] = yr;
    out[1] = yi;
}

// ---------------------------------------------------------------------------
// Kernel 2: recurrent sim — r6 structure (4 waves/chain, one barrier/step,
// VGPR-resident M split, all-VALU dots) with the instruction diet:
//   * tree: shr1/2/4/8 + bcast15/31 single-inst v_add_f32_dpp stages
//     (r0-verified) -> totals in lane 63 -> readlane(63) (r1-verified).
//     Replaces the butterfly's costly permlane swap-add stages.
//   * dpp_mov with bound_ctrl=true: folds to one v_mov_b32_dpp.
//   * packed v2f sincos in encode (r7-verified formulation).
// ---------------------------------------------------------------------------
__global__ void __launch_bounds__(256, 1) k_sim(const void* __restrict__ ang,
                                                const float* __restrict__ Mg,
                                                float* __restrict__ hbuf,
                                                const int* __restrict__ flag) {
    const int tid   = threadIdx.x;
    const int lane  = tid & 63;
    const int wv    = tid >> 6;              // wave 0..3
    const int chain = blockIdx.x;            // 0..255
    const int dir   = chain >> 7;
    const int b     = chain & 127;
    const bool bf   = (*flag != 0);

    __shared__ __align__(16) float  cl[SEQ * 12];   // 24 KB cos/sin(x)
    __shared__ __align__(16) float  zb[SEQ * NW];   // 12 KB output buffer
    __shared__ float2 pY[2][4][DIM];                // ping-pong partials, 4 KB

    // ---- stage: convert this chain's 3072 angles -> cos/sin in LDS ----
    if (!bf) {
        const float4* src =
            (const float4*)((const float*)ang + (size_t)b * (SEQ * NW));
#pragma unroll
        for (int k = 0; k < 3; ++k) {
            const int v = k * 256 + tid;          // float4 index 0..767
            const float4 a = src[v];
            __align__(16) float o[8];
            float s, c;
            __sincosf(a.x, &s, &c); o[0] = c; o[1] = s;
            __sincosf(a.y, &s, &c); o[2] = c; o[3] = s;
            __sincosf(a.z, &s, &c); o[4] = c; o[5] = s;
            __sincosf(a.w, &s, &c); o[6] = c; o[7] = s;
            ((float4*)cl)[2 * v]     = ((const float4*)o)[0];
            ((float4*)cl)[2 * v + 1] = ((const float4*)o)[1];
        }
    } else {
        const u16x8* src =
            (const u16x8*)((const uint16_t*)ang + (size_t)b * (SEQ * NW));
#pragma unroll
        for (int k = 0; k < 2; ++k) {
            const int v = k * 256 + tid;          // u16x8 index 0..383
            if (v < 384) {
                const u16x8 a = src[v];
                __align__(16) float o[16];
#pragma unroll
                for (int e = 0; e < 8; ++e) {
                    const float x = __uint_as_float(((uint32_t)a[e]) << 16);
                    float s, c;
                    __sincosf(x, &s, &c);
                    o[2 * e] = c; o[2 * e + 1] = s;
                }
#pragma unroll
                for (int j = 0; j < 4; ++j)
                    ((float4*)cl)[4 * v + j] = ((const float4*)o)[j];
            }
        }
    }

    // ---- my 16 resident M columns: row = lane, cols = 16wv..16wv+15 ----
    v2f Mres[16];
    {
        const float2* mr2 =
            (const float2*)(Mg + (size_t)(dir * 64 + lane) * 128 + 32 * wv);
#pragma unroll
        for (int k = 0; k < 16; ++k) Mres[k] = (v2f){mr2[k].x, mr2[k].y};
    }

    // per-wire Z sign masks
    int zmask[6];
#pragma unroll
    for (int w = 0; w < 6; ++w) zmask[w] = ((lane >> (5 - w)) & 1) << 31;
    const int ow0 = wv ^ 1, ow1 = wv ^ 2, ow2 = wv ^ 3;   // other waves

    float h[6] = {0.f, 0.f, 0.f, 0.f, 0.f, 0.f};

    // encode h -> my 16-col matvec partial (r6 math; packed sincos, r7 form)
    auto encode_matvec = [&](v2f& acc) {
        const v2f kc1 = {2.6041667e-3f, 2.6041667e-3f};
        const v2f kc0 = {-0.125f, -0.125f};
        const v2f ks1 = {2.6041667e-4f, 2.6041667e-4f};
        const v2f ks0 = {-2.0833333e-2f, -2.0833333e-2f};
        const v2f one = {1.f, 1.f}, half = {0.5f, 0.5f};
        v2f hp0 = {h[0], h[1]}, hp1 = {h[2], h[3]}, hp2 = {h[4], h[5]};
        v2f u0 = hp0 * hp0, u1 = hp1 * hp1, u2 = hp2 * hp2;
        v2f c0 = __builtin_elementwise_fma(u0,
                    __builtin_elementwise_fma(u0, kc1, kc0), one);
        v2f c1 = __builtin_elementwise_fma(u1,
                    __builtin_elementwise_fma(u1, kc1, kc0), one);
        v2f c2 = __builtin_elementwise_fma(u2,
                    __builtin_elementwise_fma(u2, kc1, kc0), one);
        v2f s0 = hp0 * __builtin_elementwise_fma(u0,
                    __builtin_elementwise_fma(u0, ks1, ks0), half);
        v2f s1 = hp1 * __builtin_elementwise_fma(u1,
                    __builtin_elementwise_fma(u1, ks1, ks0), half);
        v2f s2 = hp2 * __builtin_elementwise_fma(u2,
                    __builtin_elementwise_fma(u2, ks1, ks0), half);
        const float t0 = (wv & 2) ? s0.x : c0.x;   // wire0 bit = wv>>1
        const float t1 = (wv & 1) ? s0.y : c0.y;   // wire1 bit = wv&1
        const float A  = t0 * t1;
        float GH[4], GL[4];
        GH[0] = c1.x * c1.y; GH[1] = c1.x * s1.y;
        GH[2] = s1.x * c1.y; GH[3] = s1.x * s1.y;
#pragma unroll
        for (int a = 0; a < 4; ++a) GH[a] *= A;
        GL[0] = c2.x * c2.y; GL[1] = c2.x * s2.y;
        GL[2] = s2.x * c2.y; GL[3] = s2.x * s2.y;
        v2f y = {0.f, 0.f};
#pragma unroll
        for (int a = 0; a < 4; ++a) {
            v2f T = {0.f, 0.f};
#pragma unroll
            for (int b2 = 0; b2 < 4; ++b2)
                T = pkfma(GL[b2], Mres[4 * a + b2], T);
            y = pkfma(GH[a], T, y);
        }
        acc = y;
    };

    // walking pointers
    const float* cp = cl + (dir ? (SEQ - 1) * 12 : 0);
    const int   cstep = dir ? -12 : 12;
    float*       zp = zb + (dir ? (SEQ - 1) * NW : 0);
    const int   zstep = dir ? -NW : NW;

    __syncthreads();                         // staging visible

    // ---- peel: partial for t=0 (h=0) + xq preload for t=0 ----
    v2f myacc;
    encode_matvec(myacc);
    pY[0][wv][lane] = (float2){myacc.x, myacc.y};
    float4 xq0 = ((const float4*)cp)[0];
    float4 xq1 = ((const float4*)cp)[1];
    float4 xq2 = ((const float4*)cp)[2];
    cp += cstep;
    __syncthreads();                         // pY[0] visible

    for (int t = 0; t < SEQ; ++t) {
        const int buf = t & 1;

        // reassemble full y: 3 partner partials + my own
        const float2 yA = pY[buf][ow0][lane];
        const float2 yB = pY[buf][ow1][lane];
        const float2 yC = pY[buf][ow2][lane];
        const float yr = (myacc.x + yA.x) + (yB.x + yC.x);
        const float yi = (myacc.y + yA.y) + (yB.y + yC.y);
        const int yri = __float_as_int(yr), yii = __float_as_int(yi);

        // dots y[l]·y[l^m]: product trick for swaps, DPP movs otherwise
        float dot[6];
        {   // w0: xor32 — d'*s' = y[l]*y[l^32] on every lane (r6-verified)
            auto rr = __builtin_amdgcn_permlane32_swap(yri, yri, false, false);
            auto ri = __builtin_amdgcn_permlane32_swap(yii, yii, false, false);
            dot[0] = fmaf(__int_as_float((int)rr[0]), __int_as_float((int)rr[1]),
                          __int_as_float((int)ri[0]) * __int_as_float((int)ri[1]));
        }
        {   // w1: xor16
            auto rr = __builtin_amdgcn_permlane16_swap(yri, yri, false, false);
            auto ri = __builtin_amdgcn_permlane16_swap(yii, yii, false, false);
            dot[1] = fmaf(__int_as_float((int)rr[0]), __int_as_float((int)rr[1]),
                          __int_as_float((int)ri[0]) * __int_as_float((int)ri[1]));
        }
        dot[2] = fmaf(yr, dpp_mov<0x128>(yr), yi * dpp_mov<0x128>(yi)); // xor8
        dot[3] = fmaf(yr, dpp_mov<0x141>(dpp_mov<0x1B>(yr)),            // xor4
                      yi * dpp_mov<0x141>(dpp_mov<0x1B>(yi)));
        dot[4] = fmaf(yr, dpp_mov<0x4E>(yr), yi * dpp_mov<0x4E>(yi));   // xor2
        dot[5] = fmaf(yr, dpp_mov<0xB1>(yr), yi * dpp_mov<0xB1>(yi));   // xor1

        const float q = fmaf(yr, yr, yi * yi);
        const float cx[6] = {xq0.x, xq0.z, xq1.x, xq1.z, xq2.x, xq2.z};
        const float sx[6] = {xq0.y, xq0.w, xq1.y, xq1.w, xq2.y, xq2.w};

        // per-lane contribution to z_w = cx*Z_w - sx*X_w (folded, verified)
        float v[6];
#pragma unroll
        for (int w = 0; w < 6; ++w) {
            const float cq = __int_as_float(__float_as_int(cx[w] * q) ^ zmask[w]);
            v[w] = fmaf(-sx[w], dot[w], cq);
        }

        // xq for step t+1 — off the critical path, xq regs now dead
        if (t + 1 < SEQ) {
            xq0 = ((const float4*)cp)[0];
            xq1 = ((const float4*)cp)[1];
            xq2 = ((const float4*)cp)[2];
            cp += cstep;
        }

        // to-lane-63 tree (r0-verified sequence, single-inst stages)
        red6<0x111>(v);   // row_shr:1
        red6<0x112>(v);   // row_shr:2
        red6<0x114>(v);   // row_shr:4
        red6<0x118>(v);   // row_shr:8
        red6<0x142>(v);   // row_bcast:15
        red6<0x143>(v);   // row_bcast:31

        if (tid == 63) {                     // lane 63 holds the totals
#pragma unroll
            for (int w = 0; w < 6; ++w) zp[w] = v[w];
        }
        zp += zstep;
#pragma unroll
        for (int w = 0; w < 6; ++w)          // r1-verified broadcast
            h[w] = __int_as_float(
                __builtin_amdgcn_readlane(__float_as_int(v[w]), 63));

        // next state's partial into the other buffer
        encode_matvec(myacc);
        pY[buf ^ 1][wv][lane] = (float2){myacc.x, myacc.y};
        __syncthreads();                     // the ONLY barrier per step
    }

    // ---- bulk store outputs: 768 float4 over 256 threads ----
    {
        const float4* zs4 = (const float4*)zb;
        float4* go = (float4*)(hbuf + (size_t)dir * NELEM +
                               (size_t)b * (SEQ * NW));
#pragma unroll
        for (int k = 0; k < 3; ++k) {
            const int idx = tid + k * 256;
            go[idx] = zs4[idx];
        }
    }
}

// ---------------------------------------------------------------------------
// Kernel 3: out = sigmoid(fc)*h_fwd + sigmoid(bc)*h_bwd, dtype per flag.
// ---------------------------------------------------------------------------
__global__ void k_combine(const float* __restrict__ hbuf,
                          const float* __restrict__ misc,
                          void* __restrict__ out, const int* __restrict__ flag) {
    const int i = blockIdx.x * blockDim.x + threadIdx.x;
    if (i >= NELEM) return;
    const float sf = 1.f / (1.f + __expf(-misc[76]));
    const float sb = 1.f / (1.f + __expf(-misc[77]));
    const float v = sf * hbuf[i] + sb * hbuf[NELEM + i];
    if (*flag) ((__hip_bfloat16*)out)[i] = __float2bfloat16(v);
    else       ((float*)out)[i] = v;
}

// ---------------------------------------------------------------------------
extern "C" void kernel_launch(void* const* d_in, const int* in_sizes, int n_in,
                              void* d_out, int out_size, void* d_ws, size_t ws_size,
                              hipStream_t stream) {
    const void* ang  = d_in[0];
    const void* poly = d_in[1];
    const void* fp   = d_in[2];
    const void* bp   = d_in[3];
    const void* fc   = d_in[4];
    const void* bc   = d_in[5];

    // ws (floats): pad[32] | misc[128] | hbuf[2*NELEM] | Mg[16384] | flag
    float* misc = (float*)d_ws + 32;
    float* hbuf = misc + 128;
    float* Mg   = hbuf + 2 * NELEM;
    int*   flag = (int*)(Mg + 2 * 64 * 64 * 2);

    k_prep<<<33, 256, 0, stream>>>(ang, poly, fp, bp, fc, bc, misc, Mg, flag);
    k_sim<<<256, 256, 0, stream>>>(ang, Mg, hbuf, flag);
    k_combine<<<(NELEM + 255) / 256, 256, 0, stream>>>(hbuf, misc, d_out, flag);
}